// Round 7
// baseline (217.776 us; speedup 1.0000x reference)
//
#include <hip/hip_runtime.h>
#include <stdint.h>

// CIN forward, MI355X. R13: W staged through LDS to break the TLP ceiling.
// R12 post-mortem: demand model (MFMA 62 + VMEM 29 + VALU ~38 us) fits 135us
// near-serially; overlap is the gap, TLP pinned at 2 waves/SIMD because any
// work re-split halves per-wave W amortization. Fix: stage W into LDS ONCE
// per block (global_load_lds, wave-uniform dest + lane*16B = our frag layout),
// all 8 waves ds_read frags -> chip W VMEM stays 29us while wave count
// doubles (16/CU = 4/SIMD). Wave = (ot, g=dt): 2 batch-cells, acc 32 regs.
// One __syncthreads per 2-channel tile (implicit vmcnt0 drain = stage fence;
// 2 blocks/CU overlap hides it). d-sum: dt-waves combine via psum LDS.
// LDS 72.7KB (hT 35840 + wtile 32768 + psum 4096) -> 2 blocks/CU.
// Frag/pack layouts identical to correctness-verified R12.

typedef __attribute__((ext_vector_type(8))) _Float16 f16x8;
typedef __attribute__((ext_vector_type(2))) _Float16 f16x2;
typedef __attribute__((ext_vector_type(4))) float f32x4;
typedef __attribute__((ext_vector_type(16))) float f32x16;
typedef __attribute__((ext_vector_type(4))) int i32x4;
typedef __attribute__((ext_vector_type(2))) int i32x2;

union AB {
  i32x4 i;
  f16x8 h;
  uint32_t u[4];
};
union AB2 {
  i32x2 i;
  uint32_t u[2];
};

static __device__ __forceinline__ uint32_t pkmul(uint32_t a, uint32_t b) {
  f16x2 r = __builtin_bit_cast(f16x2, a) * __builtin_bit_cast(f16x2, b);
  return __builtin_bit_cast(uint32_t, r);  // one v_pk_mul_f16
}
static __device__ __forceinline__ uint32_t pkcvt(float a, float b) {
  return __builtin_bit_cast(uint32_t, __builtin_amdgcn_cvt_pkrtz(a, b));
}
static __device__ __forceinline__ void gload_lds16(const void* g, void* l) {
  __builtin_amdgcn_global_load_lds(
      (const __attribute__((address_space(1))) void*)g,
      (__attribute__((address_space(3))) void*)l, 16, 0, 0);
}

#define HP 140  // hT row: 128 ch + 12 pad (280B: 70 dw = 6 mod 32 -> 16 banks)

__global__ __launch_bounds__(512, 4) void cin_main(
    const float* __restrict__ x, const uint16_t* __restrict__ wp,
    const float* __restrict__ bias0, const float* __restrict__ bias1,
    const float* __restrict__ bias2, float* __restrict__ out) {
  __shared__ __align__(16) uint16_t hT[2][64][HP];      // [batch][d][chan]
  __shared__ __align__(16) uint16_t wtile[2][16][512];  // [slot][frag][elem]
  __shared__ float psum[2][2][128];                     // [g][batch][o]

  const int tid = threadIdx.x;
  const int w = tid >> 6, lane = tid & 63;
  const int ot = w & 3;       // wave's o-tile (0..3)
  const int g = w >> 2;       // wave's d-tile group (0: d<32, 1: d>=32)
  const int hi = lane >> 5;   // A/B k-half; C row bit (4*hi)
  const int l31 = lane & 31;  // A row (o mod 32); B/C col (d mod 32)
  const int lane8 = lane * 8;
  const int bb = blockIdx.x * 2;  // two batches per block

  // ---- stage x -> hT[p][d][m] fp16 (layer-0 h == x; 32 channels)
  for (int e = tid; e < 4096; e += 512) {
    int p = e >> 11, m = (e >> 6) & 31, d = e & 63;
    hT[p][d][m] =
        __builtin_bit_cast(uint16_t, (_Float16)x[(size_t)(bb + p) * 2048 + m * 64 + d]);
  }
  __syncthreads();

  const int drow = g * 32 + l31;  // this wave's d row in hT

  // ---- x B-frags (loop-invariant): xf[b2][s].j = x_b2[m=s*16+hi*8+j][drow]
  // b64 pairs (280B rows are 8B- but not 16B-aligned)
  AB xf[2][2];
#pragma unroll
  for (int b2 = 0; b2 < 2; ++b2)
#pragma unroll
    for (int s = 0; s < 2; ++s) {
      AB2 lo = *(const AB2*)&hT[b2][drow][s * 16 + hi * 8];
      AB2 hi4 = *(const AB2*)&hT[b2][drow][s * 16 + hi * 8 + 4];
      xf[b2][s].u[0] = lo.u[0];
      xf[b2][s].u[1] = lo.u[1];
      xf[b2][s].u[2] = hi4.u[0];
      xf[b2][s].u[3] = hi4.u[1];
    }

  f32x16 acc[2];  // [batch] : 2 chains; wave covers (ot, dt=g, b2=0..1)

  // frag ids this thread's wave stages: fi = 2w, 2w+1; fi -> (ot,cc,s) =
  // (fi>>2, (fi>>1)&1, fi&1). Reader uses index (ot<<2)|(cc<<1)|s -- match.
  const int fi0 = 2 * w, fi1 = 2 * w + 1;

#pragma unroll
  for (int L = 0; L < 3; ++L) {
    const int Kch = (L == 0) ? 32 : 128;
    const uint16_t* wl = (L == 0) ? wp : (L == 1) ? wp + 131072 : wp + 655360;
    const float* bias = (L == 0) ? bias0 : (L == 1) ? bias1 : bias2;
    const int T = Kch >> 1;  // 2 channels per tile

    // per-thread W src base for staged frags:
    // addr(fi, c) = wl + ((ot_f*Kch + cc_f) + c)*1024 + s_f*512 + lane*8
    const uint16_t* s0 = wl +
        ((size_t)((fi0 >> 2) * Kch + ((fi0 >> 1) & 1)) << 10) +
        ((fi0 & 1) << 9) + lane8;
    const uint16_t* s1 = wl +
        ((size_t)((fi1 >> 2) * Kch + ((fi1 >> 1) & 1)) << 10) +
        ((fi1 & 1) << 9) + lane8;

#pragma unroll
    for (int b2 = 0; b2 < 2; ++b2)
#pragma unroll
      for (int r = 0; r < 16; ++r) acc[b2][r] = 0.f;

    auto stage = [&](int p, int c) {
      gload_lds16(s0 + ((size_t)c << 10), &wtile[p][fi0][0]);
      gload_lds16(s1 + ((size_t)c << 10), &wtile[p][fi1][0]);
    };
    // one tile = channels c, c+1: 2cc x 2s x 2b2 = 8 MFMAs; W frags from LDS
    auto tileCompute = [&](int p, int c) {
      uint32_t hv0 = *(const uint32_t*)&hT[0][drow][c];  // ch c, c+1
      uint32_t hv1 = *(const uint32_t*)&hT[1][drow][c];
#pragma unroll
      for (int cc = 0; cc < 2; ++cc) {
        uint32_t hd0 = __builtin_amdgcn_perm(hv0, hv0,
                                             cc ? 0x03020302u : 0x01000100u);
        uint32_t hd1 = __builtin_amdgcn_perm(hv1, hv1,
                                             cc ? 0x03020302u : 0x01000100u);
#pragma unroll
        for (int s = 0; s < 2; ++s) {
          AB wf;
          wf.i = *(const i32x4*)&wtile[p][(ot << 2) | (cc << 1) | s][lane8];
          AB bf0, bf1;  // B: P[k=(c+cc)*32+s*16+hi*8+j][d] = h[c+cc,d]*x[m,d]
#pragma unroll
          for (int k = 0; k < 4; ++k) {
            bf0.u[k] = pkmul(hd0, xf[0][s].u[k]);
            bf1.u[k] = pkmul(hd1, xf[1][s].u[k]);
          }
          acc[0] = __builtin_amdgcn_mfma_f32_32x32x16_f16(wf.h, bf0.h,
                                                          acc[0], 0, 0, 0);
          acc[1] = __builtin_amdgcn_mfma_f32_32x32x16_f16(wf.h, bf1.h,
                                                          acc[1], 0, 0, 0);
        }
      }
    };

    stage(0, 0);
    __syncthreads();  // tile 0 landed (implicit vmcnt(0) drain)
#pragma unroll 1
    for (int t = 0; t < T; ++t) {
      const int p = t & 1;
      if (t + 1 < T) stage(p ^ 1, 2 * (t + 1));  // prefetch next tile
      tileCompute(p, 2 * t);
      __syncthreads();  // drains prefetch + fences slot reuse
    }

    // ---- bias + ReLU. C layout (32x32): col d = drow,
    // row o = ot*32 + (r&3) + 8*(r>>2) + 4*hi
#pragma unroll
    for (int rg = 0; rg < 4; ++rg) {
      f32x4 bv = *(const f32x4*)(bias + ot * 32 + 8 * rg + 4 * hi);
#pragma unroll
      for (int b2 = 0; b2 < 2; ++b2)
#pragma unroll
        for (int rr = 0; rr < 4; ++rr)
          acc[b2][4 * rg + rr] = fmaxf(acc[b2][4 * rg + rr] + bv[rr], 0.f);
    }

    // ---- h writeback (safe: all waves passed the final tile barrier, no
    // more hT reads this layer; visibility fenced by the psum barrier below)
    if (L < 2) {
#pragma unroll
      for (int b2 = 0; b2 < 2; ++b2)
#pragma unroll
        for (int rg = 0; rg < 4; ++rg) {
          uint2 pk;
          pk.x = pkcvt(acc[b2][4 * rg + 0], acc[b2][4 * rg + 1]);
          pk.y = pkcvt(acc[b2][4 * rg + 2], acc[b2][4 * rg + 3]);
          *(uint2*)&hT[b2][drow][ot * 32 + 8 * rg + 4 * hi] = pk;
        }
    }

    // ---- d-sum partial: xor-reduce 32 l31 lanes, stash per-(g,b2) in LDS
#pragma unroll
    for (int b2 = 0; b2 < 2; ++b2)
#pragma unroll
      for (int rg = 0; rg < 4; ++rg)
#pragma unroll
        for (int rr = 0; rr < 4; ++rr) {
          float s = acc[b2][4 * rg + rr];
          s += __shfl_xor(s, 1);
          s += __shfl_xor(s, 2);
          s += __shfl_xor(s, 4);
          s += __shfl_xor(s, 8);
          s += __shfl_xor(s, 16);
          if (l31 == 0) psum[g][b2][ot * 32 + 8 * rg + 4 * hi + rr] = s;
        }
    __syncthreads();  // psum + hT writeback visible
    if (tid < 256) {
      int p2 = tid >> 7, o = tid & 127;
      out[(size_t)(bb + p2) * 384 + L * 128 + o] =
          psum[0][p2][o] + psum[1][p2][o];
    }
    // next layer's stage(0,0)+barrier fences wtile/hT reuse; psum isn't
    // rewritten until the next layer's epilogue (after its own K-loop).
  }
}

// Pack for 32x32x16 A layout: frag (ot,c,s) elem lane*8+j holds
// W[o = ot*32 + (lane&31)][k = c*32 + s*16 + (lane>>5)*8 + j].
// Reads stay coalesced along k (thread = (o,kq), 8 consecutive floats).
// (unchanged from R9..R12 -- verified correct)
__global__ void pack_w_all(const float* __restrict__ W0, const float* __restrict__ W1,
                           const float* __restrict__ W2, uint16_t* __restrict__ Wp) {
  int blk = blockIdx.x;
  const float* W;
  uint16_t* dst;
  int kshift;  // Kch = 1<<kshift, K = 1<<(kshift+5)
  if (blk < 64)       { W = W0; dst = Wp;          kshift = 5; }
  else if (blk < 320) { W = W1; dst = Wp + 131072; kshift = 7; blk -= 64; }
  else                { W = W2; dst = Wp + 655360; kshift = 7; blk -= 320; }
  int idx = blk * 256 + threadIdx.x;
  int Kq = 1 << (kshift + 2);        // K/8
  int o = idx >> (kshift + 2);
  int kq = idx & (Kq - 1);
  int c = kq >> 2, s = (kq >> 1) & 1, hi = kq & 1;
  int ot = o >> 5, li = o & 31;
  const float* src = W + ((size_t)o << (kshift + 5)) + kq * 8;
  uint4 val;
  val.x = pkcvt(src[0], src[1]);
  val.y = pkcvt(src[2], src[3]);
  val.z = pkcvt(src[4], src[5]);
  val.w = pkcvt(src[6], src[7]);
  size_t d16 = ((((size_t)(ot << kshift) + c) * 2 + s) << 9) + (hi << 8) + (li << 3);
  *(uint4*)(dst + d16) = val;
}

extern "C" void kernel_launch(void* const* d_in, const int* in_sizes, int n_in,
                              void* d_out, int out_size, void* d_ws, size_t ws_size,
                              hipStream_t stream) {
  (void)in_sizes; (void)n_in; (void)out_size; (void)ws_size;
  const float* x  = (const float*)d_in[0];
  const float* W0 = (const float*)d_in[1];
  const float* b0 = (const float*)d_in[2];
  const float* W1 = (const float*)d_in[3];
  const float* b1 = (const float*)d_in[4];
  const float* W2 = (const float*)d_in[5];
  const float* b2 = (const float*)d_in[6];
  uint16_t* wpacked = (uint16_t*)d_ws;  // 2.25 MB of ws

  hipLaunchKernelGGL(pack_w_all, dim3(576), dim3(256), 0, stream, W0, W1, W2, wpacked);
  hipLaunchKernelGGL(cin_main, dim3(512), dim3(512), 0, stream,
                     x, wpacked, b0, b1, b2, (float*)d_out);
}